// Round 5
// baseline (268.995 us; speedup 1.0000x reference)
//
#include <hip/hip_runtime.h>

#define NF    50000
#define PADP  50001
#define KN    9
#define KTOT  2304
#define NCHUNK 782
#define NT    72          // 2304 / 32  (BK=32 K-tiles)
#define BM    224
#define NBLK  224         // 1 block/CU
#define TSZ   30720       // tile bytes: A 224x64 + B 256x64
#define RSZ   122880      // ring of 4 tiles

// ---- ws layout (bytes) ----
#define WT_OFF   0u          // 256*2304*2 = 1179648
#define FLAG_OFF 1179648u    // 4
#define CNT_OFF  1179904u    // 782*4
#define IDX_OFF  1183744u    // 450000*4
#define PADX_OFF 2983744u    // 50001*256*2

typedef float f32x4 __attribute__((ext_vector_type(4)));
typedef __bf16 bf16x8 __attribute__((ext_vector_type(8)));

typedef const __attribute__((address_space(1))) unsigned int* gas_t;
typedef __attribute__((address_space(3))) unsigned int* las_t;

static __device__ __forceinline__ void gll16(const void* g, void* l) {
  __builtin_amdgcn_global_load_lds((gas_t)g, (las_t)l, 16, 0, 0);
}

static __device__ __forceinline__ unsigned short f2bf(float f) {
  unsigned int u = __builtin_bit_cast(unsigned int, f);
  u = u + 0x7fffu + ((u >> 16) & 1u);      // RNE
  return (unsigned short)(u >> 16);
}

// ---------- preprocessing ----------

__global__ void k_pre1(const unsigned char* __restrict__ pad, int* __restrict__ cnt,
                       const unsigned int* __restrict__ raw, int* __restrict__ flag) {
  int t = blockIdx.x * 256 + threadIdx.x;
  bool ip = (t < PADP) ? (pad[t] != 0) : true;
  unsigned long long m = __ballot(ip);
  int c = t >> 6;
  if ((threadIdx.x & 63) == 0 && c < NCHUNK) cnt[c] = __popcll(m);
  if (blockIdx.x == 0 && threadIdx.x < 64) {
    unsigned int v = raw[threadIdx.x * 2 + 1];
    unsigned long long nz = __ballot(v != 0u);
    if (threadIdx.x == 0) flag[0] = (nz == 0ull) ? 1 : 0;
  }
}

// weight demodulation + transpose, fused with int64->int32 idx conversion
__global__ void k_wt(const float* __restrict__ w, unsigned short* __restrict__ wt,
                     const void* __restrict__ nbr, const int* __restrict__ flag,
                     int* __restrict__ idx32) {
  int o = blockIdx.x;
  int i = threadIdx.x;
  const float* wr = w + (o * 256 + i) * 9;
  float wv[9];
  float s = 0.f;
#pragma unroll
  for (int k = 0; k < 9; ++k) { wv[k] = wr[k]; s += wv[k] * wv[k]; }
#pragma unroll
  for (int d = 32; d >= 1; d >>= 1) s += __shfl_xor(s, d);
  __shared__ float red[4];
  if ((i & 63) == 0) red[i >> 6] = s;
  __syncthreads();
  float dc = rsqrtf(red[0] + red[1] + red[2] + red[3] + 1e-8f);
#pragma unroll
  for (int k = 0; k < 9; ++k)
    wt[o * KTOT + k * 256 + i] = f2bf(wv[k] * dc);
  const bool f64 = (flag[0] != 0);
  const long long* n64 = (const long long*)nbr;
  const int* n32 = (const int*)nbr;
  for (int e = blockIdx.x * 256 + i; e < NF * KN; e += 256 * 256)
    idx32[e] = f64 ? (int)n64[e] : n32[e];
}

// one block per 64-row chunk: prefix over cnt -> ranks -> bf16 conversion
__global__ __launch_bounds__(256) void k_rankpadx(
    const float* __restrict__ x, const unsigned char* __restrict__ pad,
    const int* __restrict__ cnt, unsigned short* __restrict__ padx) {
  const int c = blockIdx.x;
  const int tid = threadIdx.x, w = tid >> 6, lane = tid & 63;
  int s = 0;
  for (int i = tid; i < c; i += 256) s += cnt[i];
#pragma unroll
  for (int d = 32; d >= 1; d >>= 1) s += __shfl_xor(s, d);
  __shared__ int red[4];
  __shared__ int rnk[64];
  if (lane == 0) red[w] = s;
  __syncthreads();
  const int S = red[0] + red[1] + red[2] + red[3];
  if (w == 0) {
    int p = c * 64 + lane;
    bool ip = (p < PADP) ? (pad[p] != 0) : true;
    unsigned long long m = __ballot(ip);
    int before = __popcll(m & ((1ull << lane) - 1ull));
    rnk[lane] = ip ? -1 : (p - (S + before));
  }
  __syncthreads();
  const int col = lane * 4;
#pragma unroll
  for (int i = 0; i < 16; ++i) {
    int rl = i * 4 + w;
    int pp = c * 64 + rl;
    if (pp >= PADP) continue;
    int rr = rnk[rl];
    ushort4 ov;
    if (rr < 0) { ov.x = 0; ov.y = 0; ov.z = 0; ov.w = 0; }
    else {
      const float4 v = *(const float4*)(x + rr * 256 + col);
      ov.x = f2bf(v.x); ov.y = f2bf(v.y); ov.z = f2bf(v.z); ov.w = f2bf(v.w);
    }
    *(ushort4*)(padx + pp * 256 + col) = ov;
  }
}

// ---------- main gathered GEMM ----------
// BM=224 x BN=256 x BK=32, 512 thr (8 waves, 2M x 4N), wave-tile 112x64.
// Ring-4 LDS tiles of 30720B (A 224x64B + B 256x64B), ONE barrier per tile,
// fragment ping-pong: iter t reads frags(t+1) while MFMAing frags(t).
// Waves 0-6 stage A (32 rows each) + B; wave 7 stages B only (counted vmcnt per class).
__global__ __launch_bounds__(512, 2) void k_main(
    const unsigned short* __restrict__ padx,   // [50001][256] bf16
    const unsigned short* __restrict__ wt,     // [256][2304] bf16
    const int* __restrict__ idx32,             // [50000][9]
    const float* __restrict__ bias,            // [256]
    float* __restrict__ out) {                 // [50000][256] f32
  __shared__ __align__(16) unsigned char sm[130944];
  const int tid = threadIdx.x;
  const int wv = tid >> 6, lane = tid & 63;
  const int m0 = blockIdx.x * BM;
  int* idx_lds = (int*)(sm + RSZ);             // 224*9 ints

  const int q = lane & 15, hi = lane >> 4;
  const int wm = wv >> 2, wn = wv & 3;

  // preload bias (keeps vmcnt stream clean after the syncthreads)
  float bv[4];
#pragma unroll
  for (int ni = 0; ni < 4; ++ni) bv[ni] = bias[wn * 64 + ni * 16 + q];

  // idx cache
  for (int e = tid; e < BM * 9; e += 512) {
    int f = m0 + e / 9;
    if (f >= NF) f = NF - 1;
    idx_lds[e] = idx32[f * KN + (e - (e / 9) * 9)];
  }
  __syncthreads();

  // ---- staging setup: per gll16 a wave covers 16 rows x 64B, lane-linear dest ----
  const int r0 = wv * 32 + (lane >> 2);
  const int r1 = r0 + 16;
  const int srcsl = ((lane & 3) ^ ((lane >> 3) & 3)) * 8;   // swizzled source slot (elems)
  const unsigned short* wtB0 = wt + r0 * KTOT + srcsl;
  const unsigned short* wtB1 = wt + r1 * KTOT + srcsl;
  const int aD0 = wv * 2048, aD1 = aD0 + 1024;              // A dests (waves 0-6)
  const int bD0 = 14336 + wv * 2048, bD1 = bD0 + 1024;      // B dests (all waves)

  // ---- fragment read offsets (bytes within one ring buffer) ----
  const int slotb = (hi ^ ((q >> 1) & 3)) * 16;
  int aoff[7], boff[4];
#pragma unroll
  for (int mi = 0; mi < 7; ++mi) aoff[mi] = (wm * 112 + mi * 16 + q) * 64 + slotb;
#pragma unroll
  for (int ni = 0; ni < 4; ++ni) boff[ni] = 14336 + (wn * 64 + ni * 16 + q) * 64 + slotb;

  f32x4 acc[7][4];
#pragma unroll
  for (int a = 0; a < 7; ++a)
#pragma unroll
    for (int b = 0; b < 4; ++b) {
      acc[a][b][0] = 0.f; acc[a][b][1] = 0.f; acc[a][b][2] = 0.f; acc[a][b][3] = 0.f;
    }

  int pc0 = 0, pc1 = 0, pn0 = 0, pn1 = 0, pq0 = 0, pq1 = 0;
  if (wv < 7) {
    pc0 = idx_lds[r0 * 9 + 0]; pc1 = idx_lds[r1 * 9 + 0];
    pn0 = idx_lds[r0 * 9 + 1]; pn1 = idx_lds[r1 * 9 + 1];
    pq0 = pn0; pq1 = pn1;
  }

  // ---- prologue: stage tiles 0..3 (all neighbor 0) ----
#pragma unroll
  for (int u = 0; u < 4; ++u) {
    unsigned char* wb = sm + u * TSZ;
    const int kc = u * 32;
    if (wv < 7) {
      gll16(padx + pc0 * 256 + kc + srcsl, wb + aD0);
      gll16(padx + pc1 * 256 + kc + srcsl, wb + aD1);
    }
    gll16(wtB0 + u * 32, wb + bD0);
    gll16(wtB1 + u * 32, wb + bD1);
  }
  if (wv < 7) asm volatile("s_waitcnt vmcnt(8)" ::: "memory");
  else        asm volatile("s_waitcnt vmcnt(4)" ::: "memory");
  __builtin_amdgcn_s_barrier();

  bf16x8 af0[7], bf0[4], af1[7], bf1[4];
  {
    const unsigned char* rb = sm;            // frags(0) from buf 0
#pragma unroll
    for (int mi = 0; mi < 7; ++mi) af0[mi] = *(const bf16x8*)(rb + aoff[mi]);
#pragma unroll
    for (int ni = 0; ni < 4; ++ni) bf0[ni] = *(const bf16x8*)(rb + boff[ni]);
  }
  int oR = TSZ, oW = 0;

#define MFMA28(cA, cB)                                               \
  _Pragma("unroll")                                                  \
  for (int mi = 0; mi < 7; ++mi) {                                   \
    _Pragma("unroll")                                                \
    for (int ni = 0; ni < 4; ++ni)                                   \
      acc[mi][ni] = __builtin_amdgcn_mfma_f32_16x16x32_bf16(         \
          cA[mi], cB[ni], acc[mi][ni], 0, 0, 0);                     \
  }

#define ITER(J, cA, cB, nA, nB) {                                    \
  const unsigned char* rb_ = sm + oR;                                \
  _Pragma("unroll")                                                  \
  for (int mi = 0; mi < 7; ++mi) nA[mi] = *(const bf16x8*)(rb_ + aoff[mi]); \
  _Pragma("unroll")                                                  \
  for (int ni = 0; ni < 4; ++ni) nB[ni] = *(const bf16x8*)(rb_ + boff[ni]); \
  __builtin_amdgcn_sched_barrier(0);                                 \
  __builtin_amdgcn_s_setprio(1);                                     \
  MFMA28(cA, cB);                                                    \
  __builtin_amdgcn_s_setprio(0);                                     \
  __builtin_amdgcn_sched_barrier(0);                                 \
  {                                                                  \
    const int uu_ = g8 + (J) + 4;                                    \
    const int kc_ = (uu_ & 7) * 32;                                  \
    const int kg_ = ((uu_ < NT) ? uu_ : NT - 1) * 32;                \
    unsigned char* wb_ = sm + oW;                                    \
    if (wv < 7) {                                                    \
      const int p0_ = (uu_ < NT) ? (((J) < 4) ? pc0 : pn0) : 0;      \
      const int p1_ = (uu_ < NT) ? (((J) < 4) ? pc1 : pn1) : 0;      \
      gll16(padx + p0_ * 256 + kc_ + srcsl, wb_ + aD0);              \
      gll16(padx + p1_ * 256 + kc_ + srcsl, wb_ + aD1);              \
    }                                                                \
    gll16(wtB0 + kg_, wb_ + bD0);                                    \
    gll16(wtB1 + kg_, wb_ + bD1);                                    \
  }                                                                  \
  if ((J) == 0 && wv < 7) {                                          \
    const int gn_ = (g + 2 > 8) ? 8 : g + 2;                         \
    pq0 = idx_lds[r0 * 9 + gn_];                                     \
    pq1 = idx_lds[r1 * 9 + gn_];                                     \
  }                                                                  \
  if (wv < 7) asm volatile("s_waitcnt vmcnt(8)" ::: "memory");       \
  else        asm volatile("s_waitcnt vmcnt(4)" ::: "memory");       \
  asm volatile("s_waitcnt lgkmcnt(0)" ::: "memory");                 \
  __builtin_amdgcn_sched_barrier(0);                                 \
  __builtin_amdgcn_s_barrier();                                      \
  oR += TSZ; if (oR >= RSZ) oR = 0;                                  \
  oW += TSZ; if (oW >= RSZ) oW = 0;                                  \
}

  // neighbor u=t+4 crosses into g+1 when J>=4 (u=g8+J+4); tiles u>=72 are dummies.
  for (int g = 0; g < 9; ++g) {
    const int g8 = g * 8;
    ITER(0, af0, bf0, af1, bf1)
    ITER(1, af1, bf1, af0, bf0)
    ITER(2, af0, bf0, af1, bf1)
    ITER(3, af1, bf1, af0, bf0)
    ITER(4, af0, bf0, af1, bf1)
    ITER(5, af1, bf1, af0, bf0)
    ITER(6, af0, bf0, af1, bf1)
    ITER(7, af1, bf1, af0, bf0)
    if (wv < 7) { pc0 = pn0; pc1 = pn1; pn0 = pq0; pn1 = pq1; }
  }
  asm volatile("s_waitcnt vmcnt(0)" ::: "memory");

  // ---- epilogue: bias + store (D: col = q, row = hi*4 + r) ----
#pragma unroll
  for (int ni = 0; ni < 4; ++ni) {
    const int col = wn * 64 + ni * 16 + q;
#pragma unroll
    for (int mi = 0; mi < 7; ++mi) {
#pragma unroll
      for (int rr = 0; rr < 4; ++rr) {
        const int row = m0 + wm * 112 + mi * 16 + hi * 4 + rr;
        if (row < NF) out[row * 256 + col] = acc[mi][ni][rr] + bv[ni];
      }
    }
  }
#undef ITER
#undef MFMA28
}

extern "C" void kernel_launch(void* const* d_in, const int* in_sizes, int n_in,
                              void* d_out, int out_size, void* d_ws, size_t ws_size,
                              hipStream_t stream) {
  const float* x = (const float*)d_in[0];
  const float* wfull = (const float*)d_in[1];
  const float* bias = (const float*)d_in[2];
  const void* nbr = d_in[3];
  const unsigned char* pad = (const unsigned char*)d_in[4];
  float* out = (float*)d_out;
  char* ws = (char*)d_ws;

  unsigned short* wt   = (unsigned short*)(ws + WT_OFF);
  int* flag            = (int*)(ws + FLAG_OFF);
  int* cnt             = (int*)(ws + CNT_OFF);
  int* idx32           = (int*)(ws + IDX_OFF);
  unsigned short* padx = (unsigned short*)(ws + PADX_OFF);

  k_pre1<<<196, 256, 0, stream>>>(pad, cnt, (const unsigned int*)nbr, flag);
  k_wt<<<256, 256, 0, stream>>>(wfull, wt, nbr, flag, idx32);
  k_rankpadx<<<NCHUNK, 256, 0, stream>>>(x, pad, cnt, padx);
  k_main<<<NBLK, 512, 0, stream>>>(padx, wt, idx32, bias, out);
}

// Round 6
// 101.090 us; speedup vs baseline: 2.6609x; 2.6609x over previous
//
#include <hip/hip_runtime.h>

#define NF    50000
#define PADP  50001
#define KN    9
#define KTOT  2304
#define NCHUNK 782
#define NT    72          // 2304/32 K-tiles
#define BM    128
#define NBLK  391         // ceil(50000/128)
#define TSZ   24576       // tile: A 128x64B (8KB) + B 256x64B (16KB)
#define RSZ   73728       // ring-3

// ---- ws layout (bytes) ----
#define WT_OFF   0u          // 256*2304*2 = 1179648
#define FLAG_OFF 1179648u
#define CNT_OFF  1179904u    // 782*4
#define PADX_OFF 1183744u    // 50001*256*2

typedef float f32x4 __attribute__((ext_vector_type(4)));
typedef __bf16 bf16x8 __attribute__((ext_vector_type(8)));

typedef const __attribute__((address_space(1))) unsigned int* gas_t;
typedef __attribute__((address_space(3))) unsigned int* las_t;

static __device__ __forceinline__ void gll16(const void* g, void* l) {
  __builtin_amdgcn_global_load_lds((gas_t)g, (las_t)l, 16, 0, 0);
}

static __device__ __forceinline__ unsigned short f2bf(float f) {
  unsigned int u = __builtin_bit_cast(unsigned int, f);
  u = u + 0x7fffu + ((u >> 16) & 1u);      // RNE
  return (unsigned short)(u >> 16);
}

// ---------- preprocessing ----------

// fused: weight demod+transpose (blocks 0..255) | pad chunk counts + flag (blocks 256..451)
__global__ void k_prep(const float* __restrict__ w, unsigned short* __restrict__ wt,
                       const unsigned char* __restrict__ pad, int* __restrict__ cnt,
                       const unsigned int* __restrict__ raw, int* __restrict__ flag) {
  if (blockIdx.x < 256) {
    int o = blockIdx.x;
    int i = threadIdx.x;
    const float* wr = w + (o * 256 + i) * 9;
    float wv[9];
    float s = 0.f;
#pragma unroll
    for (int k = 0; k < 9; ++k) { wv[k] = wr[k]; s += wv[k] * wv[k]; }
#pragma unroll
    for (int d = 32; d >= 1; d >>= 1) s += __shfl_xor(s, d);
    __shared__ float red[4];
    if ((i & 63) == 0) red[i >> 6] = s;
    __syncthreads();
    float dc = rsqrtf(red[0] + red[1] + red[2] + red[3] + 1e-8f);
#pragma unroll
    for (int k = 0; k < 9; ++k)
      wt[o * KTOT + k * 256 + i] = f2bf(wv[k] * dc);
  } else {
    int cb = blockIdx.x - 256;
    int t = cb * 256 + threadIdx.x;
    bool ip = (t < PADP) ? (pad[t] != 0) : true;
    unsigned long long m = __ballot(ip);
    int c = t >> 6;
    if ((threadIdx.x & 63) == 0 && c < NCHUNK) cnt[c] = __popcll(m);
    if (cb == 0 && threadIdx.x < 64) {
      unsigned int v = raw[threadIdx.x * 2 + 1];
      unsigned long long nz = __ballot(v != 0u);
      if (threadIdx.x == 0) flag[0] = (nz == 0ull) ? 1 : 0;
    }
  }
}

// one block per 64-row chunk: prefix over cnt -> ranks -> bf16 conversion
__global__ __launch_bounds__(256) void k_rankpadx(
    const float* __restrict__ x, const unsigned char* __restrict__ pad,
    const int* __restrict__ cnt, unsigned short* __restrict__ padx) {
  const int c = blockIdx.x;
  const int tid = threadIdx.x, w = tid >> 6, lane = tid & 63;
  int s = 0;
  for (int i = tid; i < c; i += 256) s += cnt[i];
#pragma unroll
  for (int d = 32; d >= 1; d >>= 1) s += __shfl_xor(s, d);
  __shared__ int red[4];
  __shared__ int rnk[64];
  if (lane == 0) red[w] = s;
  __syncthreads();
  const int S = red[0] + red[1] + red[2] + red[3];
  if (w == 0) {
    int p = c * 64 + lane;
    bool ip = (p < PADP) ? (pad[p] != 0) : true;
    unsigned long long m = __ballot(ip);
    int before = __popcll(m & ((1ull << lane) - 1ull));
    rnk[lane] = ip ? -1 : (p - (S + before));
  }
  __syncthreads();
  const int col = lane * 4;
#pragma unroll
  for (int i = 0; i < 16; ++i) {
    int rl = i * 4 + w;
    int pp = c * 64 + rl;
    if (pp >= PADP) continue;
    int rr = rnk[rl];
    ushort4 ov;
    if (rr < 0) { ov.x = 0; ov.y = 0; ov.z = 0; ov.w = 0; }
    else {
      const float4 v = *(const float4*)(x + rr * 256 + col);
      ov.x = f2bf(v.x); ov.y = f2bf(v.y); ov.z = f2bf(v.z); ov.w = f2bf(v.w);
    }
    *(ushort4*)(padx + pp * 256 + col) = ov;
  }
}

// ---------- main gathered GEMM ----------
// BM=128 x BN=256 x BK=32, 512 thr (8 waves, 2M x 4N), wave-tile 64x64 (4x4).
// LDS: ring-3 x 24576B + idx cache 4608B = 78336B -> 2 blocks/CU (m114 overlap).
// Per tile: 3 uniform gll16/thread, lead-2, counted vmcnt(6), 2 raw s_barriers.
// Staging lane-linear dest (tid*16), swizzle on source: slot s of row r holds
// global slot s ^ ((r>>1)&3); fragment reads use the matching XOR.
__global__ __launch_bounds__(512, 2) void k_main(
    const unsigned short* __restrict__ padx,   // [50001][256] bf16
    const unsigned short* __restrict__ wt,     // [256][2304] bf16
    const void* __restrict__ nbr,              // [50000][9] int64 or int32
    const int* __restrict__ flag,
    const float* __restrict__ bias,            // [256]
    float* __restrict__ out) {                 // [50000][256] f32
  __shared__ __align__(16) unsigned char sm[78336];
  const int tid = threadIdx.x;
  const int wv = tid >> 6, lane = tid & 63;
  const int m0 = blockIdx.x * BM;
  int* idx_lds = (int*)(sm + RSZ);             // 128*9 ints

  const int q = lane & 15, hi = lane >> 4;
  const int wm = wv >> 2, wn = wv & 3;

  // bias preload (in-order vmem retirement: drains at first vmcnt wait)
  float bv[4];
#pragma unroll
  for (int ni = 0; ni < 4; ++ni) bv[ni] = bias[wn * 64 + ni * 16 + q];

  // idx cache (reads raw int64/int32 directly)
  const bool f64 = (flag[0] != 0);
  const long long* n64 = (const long long*)nbr;
  const int* n32 = (const int*)nbr;
  for (int e = tid; e < BM * 9; e += 512) {
    int f = m0 + e / 9;
    if (f >= NF) f = NF - 1;
    int k = e - (e / 9) * 9;
    idx_lds[e] = f64 ? (int)n64[f * KN + k] : n32[f * KN + k];
  }
  __syncthreads();

  // ---- staging setup: per gll16, wave covers 16 rows x 64B, lane-linear ----
  const int rA = tid >> 2;                                  // 0..127
  const int srcsl = ((tid & 3) ^ ((tid >> 3) & 3)) * 8;     // swizzled src slot (elems)
  const int aD  = tid * 16;                                 // A rows 0..127
  const int bD0 = 8192 + tid * 16;                          // B rows 0..127
  const int bD1 = 16384 + tid * 16;                         // B rows 128..255
  const unsigned short* wtb0 = wt + rA * KTOT + srcsl;
  const unsigned short* wtb1 = wt + (128 + rA) * KTOT + srcsl;

  // ---- fragment read offsets ----
  const int slotb = (hi ^ ((q >> 1) & 3)) * 16;
  int aoff[4], boff[4];
#pragma unroll
  for (int mi = 0; mi < 4; ++mi) aoff[mi] = (wm * 64 + mi * 16 + q) * 64 + slotb;
#pragma unroll
  for (int ni = 0; ni < 4; ++ni) boff[ni] = 8192 + (wn * 64 + ni * 16 + q) * 64 + slotb;

  f32x4 acc[4][4];
#pragma unroll
  for (int a = 0; a < 4; ++a)
#pragma unroll
    for (int b = 0; b < 4; ++b) {
      acc[a][b][0] = 0.f; acc[a][b][1] = 0.f; acc[a][b][2] = 0.f; acc[a][b][3] = 0.f;
    }

#define STAGE(u, slotbase) {                                  \
    const int c0_ = ((u) & 7) * 32;                           \
    const int gu_ = (u) >> 3;                                 \
    const int p_ = idx_lds[rA * 9 + gu_];                     \
    unsigned char* bb_ = sm + (slotbase);                     \
    const int kk_ = gu_ * 256 + c0_;                          \
    gll16(padx + p_ * 256 + c0_ + srcsl, bb_ + aD);           \
    gll16(wtb0 + kk_, bb_ + bD0);                             \
    gll16(wtb1 + kk_, bb_ + bD1); }

  // ---- prologue: stage tiles 0,1 ----
  STAGE(0, 0)
  STAGE(1, TSZ)

  int oW = 2 * TSZ;   // slot of tile t+2 at t=0
  int oR = 0;         // slot of tile t
#pragma unroll 3
  for (int t = 0; t < NT; ++t) {
    __builtin_amdgcn_sched_barrier(0);
    {
      const int u = (t + 2 < NT) ? t + 2 : NT - 1;   // tail re-stages tile 71 (safe slot)
      STAGE(u, oW)
    }
    __builtin_amdgcn_sched_barrier(0);
    // all but tiles t+1, t+2 retired -> tile t resident
    asm volatile("s_waitcnt vmcnt(6)" ::: "memory");
    __builtin_amdgcn_s_barrier();
    __builtin_amdgcn_sched_barrier(0);
    {
      const unsigned char* rb = sm + oR;
      bf16x8 af[4], bf[4];
#pragma unroll
      for (int mi = 0; mi < 4; ++mi) af[mi] = *(const bf16x8*)(rb + aoff[mi]);
#pragma unroll
      for (int ni = 0; ni < 4; ++ni) bf[ni] = *(const bf16x8*)(rb + boff[ni]);
      __builtin_amdgcn_s_setprio(1);
#pragma unroll
      for (int mi = 0; mi < 4; ++mi)
#pragma unroll
        for (int ni = 0; ni < 4; ++ni)
          acc[mi][ni] = __builtin_amdgcn_mfma_f32_16x16x32_bf16(af[mi], bf[ni], acc[mi][ni], 0, 0, 0);
      __builtin_amdgcn_s_setprio(0);
    }
    // end barrier: closes slot-reuse window (reads of slot oR done; next iter's
    // stage targets slot (t+3)%3 == oR)
    __builtin_amdgcn_s_barrier();
    oW += TSZ; if (oW == RSZ) oW = 0;
    oR += TSZ; if (oR == RSZ) oR = 0;
  }
  asm volatile("s_waitcnt vmcnt(0)" ::: "memory");
#undef STAGE

  // ---- epilogue: bias + store (D: col = q, row = hi*4 + r) ----
#pragma unroll
  for (int ni = 0; ni < 4; ++ni) {
    const int col = wn * 64 + ni * 16 + q;
#pragma unroll
    for (int mi = 0; mi < 4; ++mi) {
#pragma unroll
      for (int rr = 0; rr < 4; ++rr) {
        const int row = m0 + wm * 64 + mi * 16 + hi * 4 + rr;
        if (row < NF) out[row * 256 + col] = acc[mi][ni][rr] + bv[ni];
      }
    }
  }
}

extern "C" void kernel_launch(void* const* d_in, const int* in_sizes, int n_in,
                              void* d_out, int out_size, void* d_ws, size_t ws_size,
                              hipStream_t stream) {
  const float* x = (const float*)d_in[0];
  const float* wfull = (const float*)d_in[1];
  const float* bias = (const float*)d_in[2];
  const void* nbr = d_in[3];
  const unsigned char* pad = (const unsigned char*)d_in[4];
  float* out = (float*)d_out;
  char* ws = (char*)d_ws;

  unsigned short* wt   = (unsigned short*)(ws + WT_OFF);
  int* flag            = (int*)(ws + FLAG_OFF);
  int* cnt             = (int*)(ws + CNT_OFF);
  unsigned short* padx = (unsigned short*)(ws + PADX_OFF);

  k_prep<<<452, 256, 0, stream>>>(wfull, wt, pad, cnt, (const unsigned int*)nbr, flag);
  k_rankpadx<<<NCHUNK, 256, 0, stream>>>(x, pad, cnt, padx);
  k_main<<<NBLK, 512, 0, stream>>>(padx, wt, nbr, flag, bias, out);
}